// Round 5
// baseline (21.299 us; speedup 1.0000x reference)
//
#include <hip/hip_runtime.h>
#include <math.h>

#define TT 512
#define EE 1024
#define AA 30

typedef float    f32x4 __attribute__((ext_vector_type(4)));
typedef unsigned u32x2 __attribute__((ext_vector_type(2)));

__device__ __forceinline__ unsigned bf16rne(float f) {
    unsigned u = __float_as_uint(f);
    return (u + 0x7fffu + ((u >> 16) & 1u)) >> 16;   // RNE bf16
}
__device__ __forceinline__ float blo(unsigned u) { return __uint_as_float(u << 16); }
__device__ __forceinline__ float bhi(unsigned u) { return __uint_as_float(u & 0xffff0000u); }

// ---- Kernel 1: head = relu(x@W+b), x -> bf16 (NT stores), plus one block that
// ---- counting-sorts span ids by start[] so the span kernel can partition by XCD.
__global__ __launch_bounds__(256) void head_sort_kernel(const float* __restrict__ x,
                                                        const float* __restrict__ W,
                                                        const float* __restrict__ bias,
                                                        const int* __restrict__ start,
                                                        float* __restrict__ head,
                                                        ushort* __restrict__ x16,
                                                        int* __restrict__ order,
                                                        int BT, int S, int HB) {
    int tid = threadIdx.x;
    if ((int)blockIdx.x == HB) {
        // ---- counting sort of s in [0,S) by key start[s] in [0,TT) ----
        __shared__ int cnt[TT];
        __shared__ int wsum[4];
        for (int i = tid; i < TT; i += 256) cnt[i] = 0;
        __syncthreads();
        for (int s = tid; s < S; s += 256) {
            int k = start[s]; k = k < 0 ? 0 : (k > TT - 1 ? TT - 1 : k);
            atomicAdd(&cnt[k], 1);
        }
        __syncthreads();
        // exclusive scan over 512 bins, 2 bins/thread
        int a0 = cnt[2 * tid], a1 = cnt[2 * tid + 1];
        int pair = a0 + a1;
        int lane = tid & 63, wid = tid >> 6;
        int v = pair;
        #pragma unroll
        for (int off = 1; off < 64; off <<= 1) {
            int u = __shfl_up(v, off, 64);
            if (lane >= off) v += u;
        }
        if (lane == 63) wsum[wid] = v;
        __syncthreads();
        int base = 0;
        #pragma unroll
        for (int w = 0; w < 4; ++w) if (w < wid) base += wsum[w];
        int excl = base + v - pair;          // exclusive prefix of this thread's pair
        __syncthreads();
        cnt[2 * tid] = excl;                 // reuse cnt[] as scatter cursors
        cnt[2 * tid + 1] = excl + a0;
        __syncthreads();
        for (int s = tid; s < S; s += 256) {
            int k = start[s]; k = k < 0 ? 0 : (k > TT - 1 ? TT - 1 : k);
            int pos = atomicAdd(&cnt[k], 1);
            order[pos] = s;
        }
        return;
    }
    // ---- head rows: 1 row per wave, 4 waves/block ----
    int row  = blockIdx.x * 4 + (tid >> 6);
    int lane = tid & 63;
    if (row >= BT) return;
    const f32x4* xr = reinterpret_cast<const f32x4*>(x + (size_t)row * EE);
    const f32x4* wr = reinterpret_cast<const f32x4*>(W);
    u32x2* cr = reinterpret_cast<u32x2*>(x16 + (size_t)row * EE);
    float acc = 0.f;
    #pragma unroll
    for (int k = 0; k < 4; ++k) {
        int i = lane + 64 * k;
        f32x4 xv = xr[i];
        f32x4 wv = wr[i];
        acc += xv.x * wv.x + xv.y * wv.y + xv.z * wv.z + xv.w * wv.w;
        u32x2 pk;
        pk.x = bf16rne(xv.x) | (bf16rne(xv.y) << 16);
        pk.y = bf16rne(xv.z) | (bf16rne(xv.w) << 16);
        __builtin_nontemporal_store(pk, cr + i);   // land clean (L3), not dirty in a random L2
    }
    #pragma unroll
    for (int off = 32; off; off >>= 1) acc += __shfl_xor(acc, off, 64);
    if (lane == 0) head[row] = fmaxf(acc + bias[0], 0.0f);
}

// ---- Kernel 2: 2 spans/block from the sorted task list.
// BINNED: task g = (bid&7)*G8 + 2*(bid>>3) + {0,1}; same bid&7 -> same XCD ->
// each XCD touches one (batch x start-quantile) slice of x16 (~316 KB, L2-resident).
template <int BINNED>
__global__ __launch_bounds__(256) void span16_kernel(const ushort* __restrict__ x16,
                                                     const float* __restrict__ head,
                                                     const int* __restrict__ start,
                                                     const int* __restrict__ end,
                                                     const int* __restrict__ order,
                                                     float* __restrict__ out, int S, int G8) {
    __shared__ float wts[2][AA];
    __shared__ int sid[2], sbb[2];

    int g0 = BINNED ? ((blockIdx.x & 7) * G8 + ((blockIdx.x >> 3) << 1))
                    : (blockIdx.x * 2);

    int wv = threadIdx.x >> 6, l64 = threadIdx.x & 63;
    if (wv < 2) {                              // wave wv: softmax for task wv
        int g = g0 + wv;
        int b = g / S, r = g - b * S;
        int s = BINNED ? order[r] : r;
        if (l64 == 0) { sid[wv] = s; sbb[wv] = b; }
        int st = start[s];
        int nA = min(end[s] - st + 1, AA);
        bool valid = l64 < nA;
        int idx = st + l64; if (idx > TT - 1) idx = TT - 1;
        float sc = valid ? head[b * TT + idx] : -INFINITY;
        float m = sc;
        #pragma unroll
        for (int off = 32; off; off >>= 1) m = fmaxf(m, __shfl_xor(m, off, 64));
        float e = valid ? __expf(sc - m) : 0.0f;
        float sum = e;
        #pragma unroll
        for (int off = 32; off; off >>= 1) sum += __shfl_xor(sum, off, 64);
        if (valid) wts[wv][l64] = e / sum;
    }
    __syncthreads();

    int sp   = threadIdx.x >> 7;               // which task of the pair
    int lane = threadIdx.x & 127;              // 128 lanes x 8 bf16 = 1024 = E
    int s = sid[sp], b = sbb[sp];
    int st = start[s];
    int nA = min(end[s] - st + 1, AA);

    const uint4* xr = reinterpret_cast<const uint4*>(x16 + (size_t)b * TT * EE);
    f32x4 acc0 = (f32x4)(0.f), acc1 = (f32x4)(0.f);
    for (int a = 0; a < nA; ++a) {
        float w = wts[sp][a];
        uint4 v = xr[(size_t)(st + a) * (EE / 8) + lane];
        acc0.x += w * blo(v.x); acc0.y += w * bhi(v.x);
        acc0.z += w * blo(v.y); acc0.w += w * bhi(v.y);
        acc1.x += w * blo(v.z); acc1.y += w * bhi(v.z);
        acc1.z += w * blo(v.w); acc1.w += w * bhi(v.w);
    }
    f32x4* op = reinterpret_cast<f32x4*>(out) + (size_t)(b * S + s) * (EE / 4) + 2 * lane;
    __builtin_nontemporal_store(acc0, op);
    __builtin_nontemporal_store(acc1, op + 1);
}

// ---- fp32 fallback (workspace too small) ----
__global__ __launch_bounds__(256) void span_kernel(const float* __restrict__ x,
                                                   const float* __restrict__ head,
                                                   const int* __restrict__ start,
                                                   const int* __restrict__ end,
                                                   float* __restrict__ out, int S) {
    int bs = blockIdx.x;
    int b = bs / S, s = bs - b * S;
    int st = start[s];
    int nA = min(end[s] - st + 1, AA);
    __shared__ float wts[AA];
    int tid = threadIdx.x;
    if (tid < 64) {
        bool valid = (tid < nA);
        int idx = st + tid; if (idx > TT - 1) idx = TT - 1;
        float sc = valid ? head[b * TT + idx] : -INFINITY;
        float m = sc;
        #pragma unroll
        for (int off = 32; off; off >>= 1) m = fmaxf(m, __shfl_xor(m, off, 64));
        float e = valid ? __expf(sc - m) : 0.0f;
        float sum = e;
        #pragma unroll
        for (int off = 32; off; off >>= 1) sum += __shfl_xor(sum, off, 64);
        if (valid) wts[tid] = e / sum;
    }
    __syncthreads();
    const f32x4* xb = reinterpret_cast<const f32x4*>(x + (size_t)b * TT * EE);
    f32x4 acc = (f32x4)(0.f);
    for (int a = 0; a < nA; ++a)
        acc += wts[a] * xb[(size_t)(st + a) * (EE / 4) + tid];
    f32x4* op = reinterpret_cast<f32x4*>(out) + (size_t)bs * (EE / 4) + tid;
    __builtin_nontemporal_store(acc, op);
}

// plain head (fallback when no x16 workspace)
__global__ __launch_bounds__(256) void head_kernel(const float* __restrict__ x,
                                                   const float* __restrict__ W,
                                                   const float* __restrict__ bias,
                                                   float* __restrict__ head, int BT) {
    int row  = blockIdx.x * 4 + (threadIdx.x >> 6);
    int lane = threadIdx.x & 63;
    if (row >= BT) return;
    const f32x4* xr = reinterpret_cast<const f32x4*>(x + (size_t)row * EE);
    const f32x4* wr = reinterpret_cast<const f32x4*>(W);
    float acc = 0.f;
    #pragma unroll
    for (int i = lane; i < EE / 4; i += 64) {
        f32x4 xv = xr[i], wv = wr[i];
        acc += xv.x * wv.x + xv.y * wv.y + xv.z * wv.z + xv.w * wv.w;
    }
    #pragma unroll
    for (int off = 32; off; off >>= 1) acc += __shfl_xor(acc, off, 64);
    if (lane == 0) head[row] = fmaxf(acc + bias[0], 0.0f);
}

extern "C" void kernel_launch(void* const* d_in, const int* in_sizes, int n_in,
                              void* d_out, int out_size, void* d_ws, size_t ws_size,
                              hipStream_t stream) {
    const float* x     = (const float*)d_in[0];   // (B, T, E) f32
    const float* W     = (const float*)d_in[1];   // (E, 1)   f32
    const float* bias  = (const float*)d_in[2];   // (1,)     f32
    const int*   start = (const int*)d_in[3];     // (S,)     i32
    const int*   end   = (const int*)d_in[4];     // (S,)     i32
    float*       out   = (float*)d_out;           // (B, S, E) f32

    const int BT = in_sizes[0] / EE;              // B*T = 1024
    const int S  = in_sizes[3];                   // 2048
    const int B  = BT / TT;                       // 2
    const int G  = B * S;                         // 4096 tasks

    float* head  = (float*)d_ws;                                    // [0, 4KB)
    int*   order = (int*)((char*)d_ws + 4096);                      // [4KB, 4KB+4S)
    size_t x16off = 4096 + ((size_t)S * 4 + 255 & ~(size_t)255);
    ushort* x16  = nullptr;
    if (ws_size >= x16off + (size_t)BT * EE * sizeof(ushort))
        x16 = (ushort*)((char*)d_ws + x16off);

    const int HB = (BT + 3) / 4;
    bool binned = (x16 != nullptr) && (G % 16 == 0) && (G >= 16);

    if (x16) {
        head_sort_kernel<<<HB + 1, 256, 0, stream>>>(x, W, bias, start, head, x16, order, BT, S, HB);
        if (binned)
            span16_kernel<1><<<G / 2, 256, 0, stream>>>(x16, head, start, end, order, out, S, G / 8);
        else
            span16_kernel<0><<<G / 2, 256, 0, stream>>>(x16, head, start, end, order, out, S, G / 8);
    } else {
        head_kernel<<<HB, 256, 0, stream>>>(x, W, bias, head, BT);
        span_kernel<<<G, 256, 0, stream>>>(x, head, start, end, out, S);
    }
}

// Round 6
// 20.842 us; speedup vs baseline: 1.0219x; 1.0219x over previous
//
#include <hip/hip_runtime.h>
#include <math.h>

#define TT 512
#define EE 1024
#define AA 30

typedef float    f32x4 __attribute__((ext_vector_type(4)));
typedef unsigned u32x2 __attribute__((ext_vector_type(2)));

static __device__ __forceinline__ unsigned bf16rne(float f) {
    unsigned u = __float_as_uint(f);
    return (u + 0x7fffu + ((u >> 16) & 1u)) >> 16;   // RNE bf16
}
static __device__ __forceinline__ float blo(unsigned u) { return __uint_as_float(u << 16); }
static __device__ __forceinline__ float bhi(unsigned u) { return __uint_as_float(u & 0xffff0000u); }

// ---- Kernel 1: head = relu(x@W+b); x -> bf16 (NT stores) ----
__global__ __launch_bounds__(256) void head_kernel(const float* __restrict__ x,
                                                   const float* __restrict__ W,
                                                   const float* __restrict__ bias,
                                                   float* __restrict__ head,
                                                   ushort* __restrict__ x16, int BT) {
    int row  = blockIdx.x * 4 + (threadIdx.x >> 6);   // 1 row per wave
    int lane = threadIdx.x & 63;
    if (row >= BT) return;
    const f32x4* xr = reinterpret_cast<const f32x4*>(x + (size_t)row * EE);
    const f32x4* wr = reinterpret_cast<const f32x4*>(W);
    u32x2* cr = x16 ? reinterpret_cast<u32x2*>(x16 + (size_t)row * EE) : nullptr;
    float acc = 0.f;
    #pragma unroll
    for (int k = 0; k < 4; ++k) {
        int i = lane + 64 * k;
        f32x4 xv = xr[i];
        f32x4 wv = wr[i];
        acc += xv.x * wv.x + xv.y * wv.y + xv.z * wv.z + xv.w * wv.w;
        if (cr) {
            u32x2 pk;
            pk.x = bf16rne(xv.x) | (bf16rne(xv.y) << 16);
            pk.y = bf16rne(xv.z) | (bf16rne(xv.w) << 16);
            __builtin_nontemporal_store(pk, cr + i);
        }
    }
    #pragma unroll
    for (int off = 32; off; off >>= 1) acc += __shfl_xor(acc, off, 64);
    if (lane == 0) head[row] = fmaxf(acc + bias[0], 0.0f);
}

// ---- Kernel 2: wave-autonomous. Block = 2 spans; wave (sp,h) = span sp, column-half h.
// Each wave computes its span's softmax fully in registers (lane a holds weight a),
// then gathers its 512-element half-row slice. No LDS, no __syncthreads, no idle waves.
template <int SWZ>
__global__ __launch_bounds__(256) void span16_kernel(const ushort* __restrict__ x16,
                                                     const float* __restrict__ head,
                                                     const int* __restrict__ start,
                                                     const int* __restrict__ end,
                                                     float* __restrict__ out, int S) {
    int bid = blockIdx.x;
    int b, j2;                           // j2 = even span index within batch
    if (SWZ) {                           // bid&7 -> XCD; XCD 0-3 own b=0, 4-7 own b=1
        int xcd = bid & 7;
        b  = xcd >> 2;
        j2 = ((((bid >> 3) << 2) | (xcd & 3))) << 1;
    } else {
        int g0 = bid << 1;
        b  = g0 / S;
        j2 = g0 - b * S;
    }
    int wv   = threadIdx.x >> 6;
    int lane = threadIdx.x & 63;
    int sp   = wv >> 1;                  // which span of the pair
    int h    = wv & 1;                   // which 512-col half
    int s    = j2 + sp;

    int st = start[s];
    int nA = min(end[s] - st + 1, AA);

    // in-register softmax (wave-wide)
    bool valid = lane < nA;
    float sc = valid ? head[b * TT + st + lane] : -INFINITY;
    float m = sc;
    #pragma unroll
    for (int off = 32; off; off >>= 1) m = fmaxf(m, __shfl_xor(m, off, 64));
    float e = valid ? __expf(sc - m) : 0.0f;
    float sum = e;
    #pragma unroll
    for (int off = 32; off; off >>= 1) sum += __shfl_xor(sum, off, 64);
    float ev = e / sum;                  // lane a holds softmax weight a (0 for a>=nA)

    const uint4* xr = reinterpret_cast<const uint4*>(x16 + (size_t)b * TT * EE)
                      + h * 64 + lane;   // this wave's 1KB slice of each row
    f32x4 acc0 = (f32x4)(0.f), acc1 = (f32x4)(0.f);
    int a = 0;
    for (; a + 2 <= nA; a += 2) {        // 2 independent loads in flight per iter
        uint4 v0 = xr[(size_t)(st + a)     * (EE / 8)];
        uint4 v1 = xr[(size_t)(st + a + 1) * (EE / 8)];
        float w0 = __shfl(ev, a);
        float w1 = __shfl(ev, a + 1);
        acc0.x += w0 * blo(v0.x); acc0.y += w0 * bhi(v0.x);
        acc0.z += w0 * blo(v0.y); acc0.w += w0 * bhi(v0.y);
        acc1.x += w0 * blo(v0.z); acc1.y += w0 * bhi(v0.z);
        acc1.z += w0 * blo(v0.w); acc1.w += w0 * bhi(v0.w);
        acc0.x += w1 * blo(v1.x); acc0.y += w1 * bhi(v1.x);
        acc0.z += w1 * blo(v1.y); acc0.w += w1 * bhi(v1.y);
        acc1.x += w1 * blo(v1.z); acc1.y += w1 * bhi(v1.z);
        acc1.z += w1 * blo(v1.w); acc1.w += w1 * bhi(v1.w);
    }
    if (a < nA) {
        uint4 v0 = xr[(size_t)(st + a) * (EE / 8)];
        float w0 = __shfl(ev, a);
        acc0.x += w0 * blo(v0.x); acc0.y += w0 * bhi(v0.x);
        acc0.z += w0 * blo(v0.y); acc0.w += w0 * bhi(v0.y);
        acc1.x += w0 * blo(v0.z); acc1.y += w0 * bhi(v0.z);
        acc1.z += w0 * blo(v0.w); acc1.w += w0 * bhi(v0.w);
    }
    f32x4* op = reinterpret_cast<f32x4*>(out + (size_t)(b * S + s) * EE) + 2 * (h * 64 + lane);
    __builtin_nontemporal_store(acc0, op);
    __builtin_nontemporal_store(acc1, op + 1);
}

// ---- fp32 fallback (workspace too small for x16) ----
__global__ __launch_bounds__(256) void span_kernel(const float* __restrict__ x,
                                                   const float* __restrict__ head,
                                                   const int* __restrict__ start,
                                                   const int* __restrict__ end,
                                                   float* __restrict__ out, int S) {
    int bs = blockIdx.x;
    int b = bs / S, s = bs - b * S;
    int st = start[s];
    int nA = min(end[s] - st + 1, AA);
    __shared__ float wts[AA];
    int tid = threadIdx.x;
    if (tid < 64) {
        bool valid = (tid < nA);
        int idx = st + tid; if (idx > TT - 1) idx = TT - 1;
        float sc = valid ? head[b * TT + idx] : -INFINITY;
        float m = sc;
        #pragma unroll
        for (int off = 32; off; off >>= 1) m = fmaxf(m, __shfl_xor(m, off, 64));
        float e = valid ? __expf(sc - m) : 0.0f;
        float sum = e;
        #pragma unroll
        for (int off = 32; off; off >>= 1) sum += __shfl_xor(sum, off, 64);
        if (valid) wts[tid] = e / sum;
    }
    __syncthreads();
    const f32x4* xb = reinterpret_cast<const f32x4*>(x + (size_t)b * TT * EE);
    f32x4 acc = (f32x4)(0.f);
    for (int a = 0; a < nA; ++a)
        acc += wts[a] * xb[(size_t)(st + a) * (EE / 4) + tid];
    f32x4* op = reinterpret_cast<f32x4*>(out) + (size_t)bs * (EE / 4) + tid;
    __builtin_nontemporal_store(acc, op);
}

extern "C" void kernel_launch(void* const* d_in, const int* in_sizes, int n_in,
                              void* d_out, int out_size, void* d_ws, size_t ws_size,
                              hipStream_t stream) {
    const float* x     = (const float*)d_in[0];   // (B, T, E) f32
    const float* W     = (const float*)d_in[1];   // (E, 1)   f32
    const float* bias  = (const float*)d_in[2];   // (1,)     f32
    const int*   start = (const int*)d_in[3];     // (S,)     i32
    const int*   end   = (const int*)d_in[4];     // (S,)     i32
    float*       out   = (float*)d_out;           // (B, S, E) f32

    const int BT = in_sizes[0] / EE;              // B*T = 1024
    const int S  = in_sizes[3];                   // 2048
    const int B  = BT / TT;                       // 2
    const int G  = B * S;                         // 4096 tasks

    float*  head = (float*)d_ws;                  // BT floats
    size_t  x16off = ((size_t)BT * 4 + 255) & ~(size_t)255;
    ushort* x16  = (ws_size >= x16off + (size_t)BT * EE * 2) ? (ushort*)((char*)d_ws + x16off)
                                                             : nullptr;

    head_kernel<<<(BT + 3) / 4, 256, 0, stream>>>(x, W, bias, head, x16, BT);
    if (x16 && (S & 1) == 0) {
        if (B == 2 && S == 2048)
            span16_kernel<1><<<G / 2, 256, 0, stream>>>(x16, head, start, end, out, S);
        else
            span16_kernel<0><<<G / 2, 256, 0, stream>>>(x16, head, start, end, out, S);
    } else {
        span_kernel<<<G, 256, 0, stream>>>(x, head, start, end, out, S);
    }
}

// Round 7
// 19.603 us; speedup vs baseline: 1.0865x; 1.0632x over previous
//
#include <hip/hip_runtime.h>
#include <math.h>

#define TT 512
#define EE 1024
#define AA 30

typedef float f32x4 __attribute__((ext_vector_type(4)));

static __device__ __forceinline__ float dot4(f32x4 p, f32x4 q) {
    return p.x * q.x + p.y * q.y + p.z * q.z + p.w * q.w;
}

// Fused: per wave = one span. Online (max-free) softmax over rows:
//   sc_a = relu(x[b,st+a,:] . W + bias)  in [0, ~8]  -> exp never overflows fp32
//   out  = sum_a exp(sc_a) * x[b,st+a,:] / sum_a exp(sc_a)
// One kernel, no workspace, no inter-kernel dependency.
template <int SWZ>
__global__ __launch_bounds__(256) void fused_span_kernel(const float* __restrict__ x,
                                                         const float* __restrict__ W,
                                                         const float* __restrict__ bias,
                                                         const int* __restrict__ start,
                                                         const int* __restrict__ end,
                                                         float* __restrict__ out,
                                                         int S, int G) {
    int bid  = blockIdx.x;
    int wv   = threadIdx.x >> 6;     // 4 waves/block, 1 span/wave
    int lane = threadIdx.x & 63;
    int b, s, g;
    if (SWZ) {                       // bid&7 -> XCD; XCD 0-3 own b=0, XCD 4-7 own b=1
        int xcd = bid & 7;
        b = xcd >> 2;
        int local = ((bid >> 3) << 2) | (xcd & 3);   // [0, S/4)
        s = local * 4 + wv;
        g = b * S + s;
    } else {
        g = bid * 4 + wv;
        if (g >= G) return;
        b = g / S;
        s = g - b * S;
    }

    int st = start[s];
    int nA = min(end[s] - st + 1, AA);   // >=1; valid rows need no clamp (end <= T-1)

    // lane's slice: elements [4*lane + 256*c], c = 0..3  (wave covers all 1024)
    const f32x4* xb = reinterpret_cast<const f32x4*>(x + ((size_t)b * TT + st) * EE) + lane;
    const f32x4* wp = reinterpret_cast<const f32x4*>(W) + lane;

    f32x4 w0 = wp[0], w1 = wp[64], w2 = wp[128], w3 = wp[192];
    f32x4 a0 = (f32x4)(0.f), a1 = (f32x4)(0.f), a2 = (f32x4)(0.f), a3 = (f32x4)(0.f);
    float sum = 0.f;
    float bsc = bias[0];

    int a = 0;
    for (; a + 2 <= nA; a += 2) {        // 8 independent loads in flight
        const f32x4* r0 = xb + (size_t)a * (EE / 4);
        const f32x4* r1 = r0 + (EE / 4);
        f32x4 v0 = r0[0], v1 = r0[64], v2 = r0[128], v3 = r0[192];
        f32x4 u0 = r1[0], u1 = r1[64], u2 = r1[128], u3 = r1[192];
        float d0 = dot4(v0, w0) + dot4(v1, w1) + dot4(v2, w2) + dot4(v3, w3);
        float d1 = dot4(u0, w0) + dot4(u1, w1) + dot4(u2, w2) + dot4(u3, w3);
        #pragma unroll
        for (int off = 32; off; off >>= 1) {     // two interleaved butterflies
            d0 += __shfl_xor(d0, off, 64);
            d1 += __shfl_xor(d1, off, 64);
        }
        float p0 = __expf(fmaxf(d0 + bsc, 0.f));
        float p1 = __expf(fmaxf(d1 + bsc, 0.f));
        sum += p0 + p1;
        a0 += p0 * v0 + p1 * u0;
        a1 += p0 * v1 + p1 * u1;
        a2 += p0 * v2 + p1 * u2;
        a3 += p0 * v3 + p1 * u3;
    }
    if (a < nA) {
        const f32x4* r0 = xb + (size_t)a * (EE / 4);
        f32x4 v0 = r0[0], v1 = r0[64], v2 = r0[128], v3 = r0[192];
        float d0 = dot4(v0, w0) + dot4(v1, w1) + dot4(v2, w2) + dot4(v3, w3);
        #pragma unroll
        for (int off = 32; off; off >>= 1) d0 += __shfl_xor(d0, off, 64);
        float p0 = __expf(fmaxf(d0 + bsc, 0.f));
        sum += p0;
        a0 += p0 * v0;
        a1 += p0 * v1;
        a2 += p0 * v2;
        a3 += p0 * v3;
    }

    float inv = 1.0f / sum;              // sum >= exp(sc_0) >= 1, uniform across lanes
    f32x4* op = reinterpret_cast<f32x4*>(out + (size_t)g * EE) + lane;
    __builtin_nontemporal_store(a0 * inv, op);
    __builtin_nontemporal_store(a1 * inv, op + 64);
    __builtin_nontemporal_store(a2 * inv, op + 128);
    __builtin_nontemporal_store(a3 * inv, op + 192);
}

extern "C" void kernel_launch(void* const* d_in, const int* in_sizes, int n_in,
                              void* d_out, int out_size, void* d_ws, size_t ws_size,
                              hipStream_t stream) {
    const float* x     = (const float*)d_in[0];   // (B, T, E) f32
    const float* W     = (const float*)d_in[1];   // (E, 1)   f32
    const float* bias  = (const float*)d_in[2];   // (1,)     f32
    const int*   start = (const int*)d_in[3];     // (S,)     i32
    const int*   end   = (const int*)d_in[4];     // (S,)     i32
    float*       out   = (float*)d_out;           // (B, S, E) f32

    const int BT = in_sizes[0] / EE;              // B*T = 1024
    const int S  = in_sizes[3];                   // 2048
    const int B  = BT / TT;                       // 2
    const int G  = B * S;                         // 4096 spans

    if (B == 2 && S == 2048) {
        fused_span_kernel<1><<<G / 4, 256, 0, stream>>>(x, W, bias, start, end, out, S, G);
    } else {
        fused_span_kernel<0><<<(G + 3) / 4, 256, 0, stream>>>(x, W, bias, start, end, out, S, G);
    }
}